// Round 17
// baseline (833.133 us; speedup 1.0000x reference)
//
#include <hip/hip_runtime.h>
#include <hip/hip_fp16.h>
#include <math.h>

// NODE_DIM=3, EMBED=16
#define ND 3
#define EM 16
#define BQ 512        // nodes per bucket (power of 2)
#define BQ_SH 9
#define MAXB 1024     // max buckets => supports N <= 524288
#define CHK 8192      // edges per edge_bin block (16 per thread @512)
#define COLS 12288    // LDS staging bound (mean bucket edges ~8192, +45 sigma)
// packed pair: (dst & 511) << 23 | src
#define P_SH 23
#define PMASK ((1u << P_SH) - 1)
// packed cw: (wq << 19) | src  (src < 2^19 since N <= 524288;
// wq = round(w * 256), 13 bits, saturating -> w in [0, 32), res 1/256)
#define CW_SH 19
#define CW_SRCM ((1u << CW_SH) - 1)
#define WSCALE 256.0f
#define WINV (1.0f / 256.0f)
// src ranges for phased conv: 8 ranges of 65536 nodes (2MB fp16 z each)
#define RSH 16

__device__ __forceinline__ float sp(float x) {
    // jax.nn.softplus = max(x,0) + log1p(exp(-|x|))
    return fmaxf(x, 0.0f) + log1pf(expf(-fabsf(x)));
}

// Kernel 0: zero bucket counters.
__global__ __launch_bounds__(1024) void bucket_zero(int* __restrict__ bcnt)
{
    bcnt[threadIdx.x] = 0;
}

// Kernel A: bucket histogram of dst (bucket = dst >> 9).
__global__ __launch_bounds__(256) void bucket_count(
    const int* __restrict__ ei, int* __restrict__ bcnt, int E, int NB)
{
    __shared__ int h[MAXB];
    int t = threadIdx.x;
    for (int i = t; i < MAXB; i += 256) h[i] = 0;
    __syncthreads();
    const int* dp = ei + (size_t)E;
    for (int e = blockIdx.x * 256 + t; e < E; e += gridDim.x * 256)
        atomicAdd(&h[((unsigned)dp[e]) >> BQ_SH], 1);
    __syncthreads();
    for (int i = t; i < NB; i += 256) {
        int v = h[i];
        if (v) atomicAdd(&bcnt[i], v);
    }
}

// Kernel B: exclusive scan of bucket counts (NB <= 1024) -> gbase, gcur.
__global__ __launch_bounds__(1024) void bucket_scan(
    const int* __restrict__ bcnt, int* __restrict__ gbase,
    int* __restrict__ gcur, int NB)
{
    __shared__ int sd[1024];
    int t = threadIdx.x;
    int v = (t < NB) ? bcnt[t] : 0;
    sd[t] = v;
    __syncthreads();
    for (int off = 1; off < 1024; off <<= 1) {
        int add = (t >= off) ? sd[t - off] : 0;
        __syncthreads();
        sd[t] += add;
        __syncthreads();
    }
    if (t < NB) { int ex = sd[t] - v; gbase[t] = ex; gcur[t] = ex; }
}

// Kernel C (512 threads): bin edges into bucket-contiguous packed-pair runs,
// LDS-sorted per chunk so global writes are in-order & coalesced.
__global__ __launch_bounds__(512) void edge_bin(
    const int* __restrict__ ei, int* __restrict__ gcur,
    unsigned int* __restrict__ pairs, int E)
{
    __shared__ int lcnt[MAXB];
    __shared__ int lbase[MAXB];
    __shared__ int sbase[MAXB];
    __shared__ unsigned int stage[CHK];
    __shared__ unsigned short bid[CHK];
    __shared__ int sd[512];
    int t = threadIdx.x;
    int c0 = blockIdx.x * CHK;
    int cntT = min(CHK, E - c0);
    for (int i = t; i < MAXB; i += 512) lcnt[i] = 0;
    __syncthreads();
    const int* dp = ei + (size_t)E;
    int dreg[16];
#pragma unroll
    for (int it = 0; it < 16; it++) {
        int e = c0 + it * 512 + t;
        dreg[it] = (e < E) ? dp[e] : 0;
        if (e < E) atomicAdd(&lcnt[((unsigned)dreg[it]) >> BQ_SH], 1);
    }
    __syncthreads();
    int b2 = t * 2;
    int h0 = lcnt[b2], h1 = lcnt[b2 + 1];
    int s2 = h0 + h1;
    sd[t] = s2;
    __syncthreads();
    for (int off = 1; off < 512; off <<= 1) {
        int add = (t >= off) ? sd[t - off] : 0;
        __syncthreads();
        sd[t] += add;
        __syncthreads();
    }
    int ex = sd[t] - s2;
    lbase[b2]     = ex;
    lbase[b2 + 1] = ex + h0;
    sbase[b2]     = h0 ? atomicAdd(&gcur[b2], h0)     : 0;
    sbase[b2 + 1] = h1 ? atomicAdd(&gcur[b2 + 1], h1) : 0;
    lcnt[b2] = 0; lcnt[b2 + 1] = 0;
    __syncthreads();
#pragma unroll
    for (int it = 0; it < 16; it++) {
        int e = c0 + it * 512 + t;
        if (e < E) {
            int d = dreg[it];
            unsigned b = ((unsigned)d) >> BQ_SH;
            int s = ei[e];
            int pos = lbase[b] + atomicAdd(&lcnt[b], 1);
            stage[pos] = ((unsigned)(d & (BQ - 1)) << P_SH) | (unsigned)s;
            bid[pos] = (unsigned short)b;
        }
    }
    __syncthreads();
    for (int i = t; i < cntT; i += 512) {
        unsigned b = bid[i];
        pairs[sbase[b] + (i - lbase[b])] = stage[i];
    }
}

// Kernel D (512 threads, fused): per-bucket CSR build with (node,range)
// ordering + edge weights + dinv + node_init + rp8 range-boundary table.
// Edges within each node's slab are sorted by src-range (src>>16) so the
// phased conv can sweep ranges with per-node cursors. cw written fully
// coalesced via LDS restage. rp8[n] = 8 u16 inclusive per-range cumulative
// counts (word3 hi16 = total deg).
__global__ __launch_bounds__(512) void bucket_csr_init(
    const unsigned int* __restrict__ pairs, const int* __restrict__ gbase,
    const int* __restrict__ bcnt, const float* __restrict__ pos,
    const float* __restrict__ W_init, const float* __restrict__ b_init,
    const float* __restrict__ W_g1,
    int* __restrict__ rowptr, unsigned int* __restrict__ cw,
    float* __restrict__ dinv, __half2* __restrict__ zh1,
    uint4* __restrict__ rp8, int N, int NB)
{
    __shared__ int nrc[BQ * 8];       // 16KB: (node,range) counts->bases->cur
    __shared__ float wsum[BQ];
    __shared__ int sd[512];
    __shared__ unsigned int stg[COLS];
    __shared__ float posS[BQ * 3];
    __shared__ float sWi[ND * EM];
    __shared__ float sbi[EM];
    __shared__ float sW1[EM * EM];
    __shared__ float lx[64][EM + 2];
    int b = blockIdx.x;
    int t = threadIdx.x;
    int lo = b << BQ_SH;
    int hi = min(lo + BQ, N);
    int nloc = hi - lo;
    int r0 = gbase[b];
    int cntE = bcnt[b];
    if (t < ND * EM)  sWi[t] = W_init[t];
    if (t < EM)       sbi[t] = b_init[t];
    if (t < EM * EM)  sW1[t] = W_g1[t];
    for (int i = t; i < 3 * nloc; i += 512) posS[i] = pos[(size_t)lo * 3 + i];
    for (int i = t; i < BQ * 8; i += 512) nrc[i] = 0;
    wsum[t] = 0.0f;
    __syncthreads();
    for (int i = t; i < cntE; i += 512) {
        unsigned p = pairs[r0 + i];
        int key = (int)((p >> P_SH) << 3) | (int)((p & PMASK) >> RSH);
        atomicAdd(&nrc[key], 1);
    }
    __syncthreads();
    // per-node local scan over 8 ranges + block scan over node totals
    int lc[8], lex[8];
    int run = 0;
#pragma unroll
    for (int r = 0; r < 8; r++) {
        lc[r] = nrc[t * 8 + r];
        lex[r] = run;
        run += lc[r];
    }
    sd[t] = run;
    __syncthreads();
    for (int off = 1; off < 512; off <<= 1) {
        int add = (t >= off) ? sd[t - off] : 0;
        __syncthreads();
        sd[t] += add;
        __syncthreads();
    }
    int exG = sd[t] - run;
#pragma unroll
    for (int r = 0; r < 8; r++) nrc[t * 8 + r] = exG + lex[r];
    if (lo + t < hi) {
        rowptr[lo + t] = r0 + exG;
        unsigned cm[8];
#pragma unroll
        for (int r = 0; r < 8; r++) cm[r] = (unsigned)(lex[r] + lc[r]);
        rp8[lo + t] = make_uint4(cm[0] | (cm[1] << 16), cm[2] | (cm[3] << 16),
                                 cm[4] | (cm[5] << 16), cm[6] | (cm[7] << 16));
    }
    if (b == NB - 1 && t == 0) rowptr[N] = r0 + cntE;  // == E
    __syncthreads();
    bool fit = (cntE <= COLS);
    if (fit) {
        for (int i = t; i < cntE; i += 512) {
            unsigned p = pairs[r0 + i];
            int key = (int)((p >> P_SH) << 3) | (int)((p & PMASK) >> RSH);
            int slot = atomicAdd(&nrc[key], 1);
            stg[slot] = p;
        }
        __syncthreads();
        for (int i = t; i < cntE; i += 512) {
            unsigned p = stg[i];
            int ldst = (int)(p >> P_SH);
            int src = (int)(p & PMASK);
            float dx = posS[ldst * 3 + 0] - pos[(size_t)src * 3 + 0];
            float dy = posS[ldst * 3 + 1] - pos[(size_t)src * 3 + 1];
            float dz = posS[ldst * 3 + 2] - pos[(size_t)src * 3 + 2];
            float d = sqrtf(fmaf(dx, dx, fmaf(dy, dy, dz * dz)));
            unsigned wq = (unsigned)fminf(fmaf(d, WSCALE, 0.5f), 8191.0f);
            cw[r0 + i] = (unsigned)src | (wq << CW_SH);
            atomicAdd(&wsum[ldst], d);
        }
    } else {
        // overflow fallback (practically unreachable)
        for (int i = t; i < cntE; i += 512) {
            unsigned p = pairs[r0 + i];
            int ldst = (int)(p >> P_SH);
            int src = (int)(p & PMASK);
            int key = (ldst << 3) | (src >> RSH);
            int slot = atomicAdd(&nrc[key], 1);
            float dx = posS[ldst * 3 + 0] - pos[(size_t)src * 3 + 0];
            float dy = posS[ldst * 3 + 1] - pos[(size_t)src * 3 + 1];
            float dz = posS[ldst * 3 + 2] - pos[(size_t)src * 3 + 2];
            float d = sqrtf(fmaf(dx, dx, fmaf(dy, dy, dz * dz)));
            unsigned wq = (unsigned)fminf(fmaf(d, WSCALE, 0.5f), 8191.0f);
            cw[r0 + slot] = (unsigned)src | (wq << CW_SH);
            atomicAdd(&wsum[ldst], d);
        }
    }
    __syncthreads();
    // epilogue: dinv + fused node_init -> zh1, 8-lane groups (low VGPR).
    int g = t >> 3, c = t & 7;          // 64 groups x 8 lanes
    for (int j = 0; j < BQ / 64; j++) {
        int nl = j * 64 + g;
        if (nl < nloc) {
            float p0 = posS[nl * 3 + 0];
            float p1 = posS[nl * 3 + 1];
            float p2 = posS[nl * 3 + 2];
            int k0 = 2 * c, k1 = 2 * c + 1;
            float h0 = fmaf(p0, sWi[0 * EM + k0],
                       fmaf(p1, sWi[1 * EM + k0],
                       fmaf(p2, sWi[2 * EM + k0], sbi[k0])));
            float h1 = fmaf(p0, sWi[0 * EM + k1],
                       fmaf(p1, sWi[1 * EM + k1],
                       fmaf(p2, sWi[2 * EM + k1], sbi[k1])));
            lx[g][k0] = sp(h0);
            lx[g][k1] = sp(h1);
            float di = rsqrtf(1.0f + wsum[nl]);
            int n = lo + nl;
            if (c == 0) dinv[n] = di;
            float ax = 0.0f, ay = 0.0f;
#pragma unroll
            for (int jj = 0; jj < EM; jj++) {
                float lj = lx[g][jj];
                ax = fmaf(lj, sW1[jj * EM + k0], ax);
                ay = fmaf(lj, sW1[jj * EM + k1], ay);
            }
            zh1[(size_t)n * 8 + c] =
                __float22half2_rn(make_float2(ax * di, ay * di));
        }
    }
}

// Kernel 6 (x2): PHASED fused GCN-mean layer. 256-thr blocks, 32 groups x
// 8 lanes; each group owns 8 nodes with register accumulators acc[8] and
// per-node cursors. Sweeps src-ranges r=0..7 (edges range-sorted per node,
// boundaries from rp8 via shfl): all ~1954 blocks are co-resident
// (launch_bounds 256,8 -> 2048 capacity), so at any instant each XCD's z
// gather working set is ~one 2MB range slice (L2-resident) instead of the
// whole 16MB table. 8 independent chains per group preserve MLP.
// mode 1: zout = fp16((x@W)*di); mode 2: fused head -> out.
__global__ __launch_bounds__(256, 8) void gather_conv(
    const int* __restrict__ rowptr, const unsigned int* __restrict__ cw,
    const uint4* __restrict__ rp8, const float* __restrict__ dinv,
    const __half2* __restrict__ zin, const float* __restrict__ bconv,
    const float* __restrict__ W,
    const float* __restrict__ P1, const float* __restrict__ b1,
    const float* __restrict__ P2, const float* __restrict__ b2,
    const float* __restrict__ sig,
    __half2* __restrict__ zout, float* __restrict__ out, int N, int mode)
{
    __shared__ float sW[EM * EM];
    __shared__ float sP2[EM * ND];
    __shared__ float sb1[EM];
    __shared__ float sb2[ND];
    __shared__ float lx[32][EM + 1];
    int t = threadIdx.x;
    if (mode == 1) {
        sW[t] = W[t];
    } else {
        sW[t] = P1[t];
        if (t < EM)      sb1[t] = b1[t];
        if (t < EM * ND) sP2[t] = P2[t];
        if (t < ND)      sb2[t] = b2[t];
    }
    int g = t >> 3, c = t & 7;          // 32 groups x 8 lanes
    int nb = blockIdx.x * 256 + g * 8;  // group's first node
    int myn = nb + c;                   // lane c is loader for node nb+c
    int myStart = 0;
    uint4 rr = make_uint4(0u, 0u, 0u, 0u);
    if (myn < N) { myStart = rowptr[myn]; rr = rp8[myn]; }
    unsigned u0 = rr.x, u1 = rr.y, u2 = rr.z, u3 = rr.w;
    int j[8], en[8];
    float ax[8], ay[8];
#pragma unroll
    for (int k = 0; k < 8; k++) {
        j[k] = __shfl(myStart, k, 8);
        ax[k] = 0.0f; ay[k] = 0.0f;
    }
#pragma unroll
    for (int r = 0; r < 8; r++) {
        unsigned wsel = (r < 2) ? u0 : (r < 4) ? u1 : (r < 6) ? u2 : u3;
        unsigned myc = (r & 1) ? (wsel >> 16) : (wsel & 0xFFFFu);
        int mye = myStart + (int)myc;
#pragma unroll
        for (int k = 0; k < 8; k++) en[k] = __shfl(mye, k, 8);
        for (;;) {
            bool any = false;
#pragma unroll
            for (int k = 0; k < 8; k++) {
                if (j[k] < en[k]) {
                    unsigned p = cw[j[k]];
                    float2 z =
                        __half22float2(zin[(size_t)(p & CW_SRCM) * 8 + c]);
                    float wv = (float)(p >> CW_SH) * WINV;
                    ax[k] = fmaf(wv, z.x, ax[k]);
                    ay[k] = fmaf(wv, z.y, ay[k]);
                    j[k]++;
                    any = true;
                }
            }
            if (!any) break;
        }
        __syncthreads();   // soft range-lockstep within block
    }
    int mydeg = (int)(u3 >> 16);        // total deg (inclusive cum of r=7)
    // epilogue: per owned node k, finish + channel-mix via lx exchange
#pragma unroll
    for (int k = 0; k < 8; k++) {
        int n = nb + k;
        float xx = 0.0f, xy = 0.0f, di = 1.0f;
        if (n < N) {
            di = dinv[n];
            float2 s = __half22float2(zin[(size_t)n * 8 + c]);  // self loop
            int dg = __shfl(mydeg, k, 8);
            float rc = 1.0f / (float)(dg + 1);
            xx = sp(fmaf((ax[k] + s.x) * di, rc, bconv[2 * c]));
            xy = sp(fmaf((ay[k] + s.y) * di, rc, bconv[2 * c + 1]));
        }
        __syncthreads();
        lx[g][2 * c]     = xx;
        lx[g][2 * c + 1] = xy;
        __syncthreads();
        if (n < N) {
            if (mode == 1) {
                float axx = 0.0f, ayy = 0.0f;
#pragma unroll
                for (int jj = 0; jj < EM; jj++) {
                    float lj = lx[g][jj];
                    axx = fmaf(lj, sW[jj * EM + 2 * c], axx);
                    ayy = fmaf(lj, sW[jj * EM + 2 * c + 1], ayy);
                }
                zout[(size_t)n * 8 + c] =
                    __float22half2_rn(make_float2(axx * di, ayy * di));
            } else {
                float axx = sb1[2 * c], ayy = sb1[2 * c + 1];
#pragma unroll
                for (int jj = 0; jj < EM; jj++) {
                    float lj = lx[g][jj];
                    axx = fmaf(lj, sW[jj * EM + 2 * c], axx);
                    ayy = fmaf(lj, sW[jj * EM + 2 * c + 1], ayy);
                }
                lx[g][2 * c]     = sp(axx);   // wave-lockstep safe
                lx[g][2 * c + 1] = sp(ayy);
                if (c < ND) {
                    float o = sb2[c];
#pragma unroll
                    for (int jj = 0; jj < EM; jj++)
                        o = fmaf(lx[g][jj], sP2[jj * ND + c], o);
                    out[(size_t)n * ND + c] = o / sig[n];
                }
            }
        }
    }
}

extern "C" void kernel_launch(void* const* d_in, const int* in_sizes, int n_in,
                              void* d_out, int out_size, void* d_ws, size_t ws_size,
                              hipStream_t stream) {
    const float* pos    = (const float*)d_in[0];
    const float* sig    = (const float*)d_in[1];
    const int*   ei     = (const int*)d_in[2];
    const float* W_init = (const float*)d_in[4];
    const float* b_init = (const float*)d_in[5];
    const float* W_g1   = (const float*)d_in[6];
    const float* b_g1   = (const float*)d_in[7];
    const float* W_g2   = (const float*)d_in[8];
    const float* b_g2   = (const float*)d_in[9];
    const float* W_p1   = (const float*)d_in[10];
    const float* b_p1   = (const float*)d_in[11];
    const float* W_p2   = (const float*)d_in[12];
    const float* b_p2   = (const float*)d_in[13];
    float* out = (float*)d_out;

    int N = in_sizes[0] / ND;
    int E = in_sizes[2] / 2;
    size_t Ns = (size_t)N, Es = (size_t)E;
    int NB = (N + BQ - 1) >> BQ_SH;   // <= MAXB for N <= 524288

    // Workspace layout (4B elements):
    // rowptr[N+1] | bcnt[1024] | gbase[1024] | gcur[1024] | dinv[N]
    //   | cw[E] (u32) | pairs[E] (u32) | zh1[8N] (half2) | rp8[N] (uint4)
    // zh2 (8N half2 = 16MB) aliases pairs (32MB, dead after bucket_csr_init).
    int* rowptr = (int*)d_ws;
    int* bcnt   = rowptr + (Ns + 1);
    int* gbase  = bcnt + 1024;
    int* gcur   = gbase + 1024;
    float* dinv = (float*)(gcur + 1024);
    unsigned int* cw = (unsigned int*)(dinv + Ns);
    unsigned int* pairs = cw + Es;
    __half2* zh2 = (__half2*)pairs;
    unsigned int* zh1w = pairs + Es;
    __half2* zh1 = (__half2*)zh1w;
    size_t rpoff = (size_t)(zh1w - (unsigned int*)d_ws) + 8 * Ns;
    rpoff = (rpoff + 3) & ~(size_t)3;     // 16B align
    uint4* rp8 = (uint4*)((unsigned int*)d_ws + rpoff);

    int nbG2 = (N + 255) / 256;         // phased conv: 256 nodes/block
    int nbBin = (E + CHK - 1) / CHK;

    bucket_zero<<<1, 1024, 0, stream>>>(bcnt);
    bucket_count<<<1024, 256, 0, stream>>>(ei, bcnt, E, NB);
    bucket_scan<<<1, 1024, 0, stream>>>(bcnt, gbase, gcur, NB);
    edge_bin<<<nbBin, 512, 0, stream>>>(ei, gcur, pairs, E);
    bucket_csr_init<<<NB, 512, 0, stream>>>(pairs, gbase, bcnt, pos,
        W_init, b_init, W_g1, rowptr, cw, dinv, zh1, rp8, N, NB);
    gather_conv<<<nbG2, 256, 0, stream>>>(rowptr, cw, rp8, dinv, zh1, b_g1,
        W_g2, W_p1, b_p1, W_p2, b_p2, sig, zh2, out, N, 1);
    gather_conv<<<nbG2, 256, 0, stream>>>(rowptr, cw, rp8, dinv, zh2, b_g2,
        W_g2, W_p1, b_p1, W_p2, b_p2, sig, zh2, out, N, 2);
}